// Round 11
// baseline (47.865 us; speedup 1.0000x reference)
//
#include <hip/hip_runtime.h>

#define N_NODES 100000
#define N_EDGES 640000
#define HIDDEN  128

#define NB    400              // nodes per bucket (doubled vs r10)
#define NBKT  250              // buckets; NB*NBKT == N_NODES
#define PB    250              // partition blocks
#define PT    512              // partition threads (8 waves/block)
#define EPT   5                // edges/thread: PB*PT*EPT == N_EDGES
#define BLK_RECS (PT * EPT)    // 2560 records per partition block
#define CT    512              // consumer threads
#define RUNOF_CAP 3072         // run_of entries (mean cnt 2560, sigma~51, 10s)
#define CAP2  3072             // compacted per-bucket record capacity
#define BSROW (NBKT + 1)       // bs_t row stride (incl. sentinel)

// ---------------------------------------------------------------------------
// Partition (+weight prep in block 0).
// Each block LDS-sorts its 2560 edge records by dst bucket, then:
//   - streams them to its OWN region recs[pb*2560..] (fully coalesced)
//   - writes its 251-entry offset row bs_t[pb][.] contiguously (coalesced).
// Record: x = src | (dst_local << 17)  (src<2^17, dl<400<2^9), y = w bits.
// ---------------------------------------------------------------------------
__global__ __launch_bounds__(PT) void partition_kernel(
    const int* __restrict__ ei, const float* __restrict__ ea,
    const float* __restrict__ W1_rel, const float* __restrict__ b1,
    const float* __restrict__ W1_root, const float* __restrict__ W2_rel,
    const float* __restrict__ W2_root,
    uint2* __restrict__ recs, int* __restrict__ bs_t,
    float* __restrict__ packed) {
    const int tid = threadIdx.x;
    const int pb  = blockIdx.x;

    if (pb == 0 && tid < HIDDEN) {
        float* p = packed + tid * 12;
#pragma unroll
        for (int k = 0; k < 4; ++k) p[k]     = W1_rel[k * HIDDEN + tid];
#pragma unroll
        for (int k = 0; k < 4; ++k) p[4 + k] = W1_root[k * HIDDEN + tid];
        p[8]  = b1[tid];
        p[9]  = W2_rel[tid];
        p[10] = W2_root[tid];
        p[11] = 0.f;
    }

    __shared__ int   hist[NBKT];
    __shared__ int   start[NBKT];
    __shared__ int   wcur[NBKT];
    __shared__ uint2 srec[BLK_RECS];   // 20 KB

    for (int i = tid; i < NBKT; i += PT) hist[i] = 0;
    __syncthreads();

    int   dsts[EPT];
    int   srcs[EPT];
    float wts[EPT];
    const int e0 = pb * BLK_RECS + tid;
#pragma unroll
    for (int k = 0; k < EPT; ++k) {
        int e = e0 + k * PT;
        srcs[k] = ei[e];
        dsts[k] = ei[N_EDGES + e];
        wts[k]  = ea[e];
        atomicAdd(&hist[dsts[k] / NB], 1);
    }
    __syncthreads();

    // Single-wave exclusive scan of hist -> start/wcur (4 chunks of 64).
    if (tid < 64) {
        int base = 0;
        for (int c = 0; c < NBKT; c += 64) {
            int idx = c + tid;
            int v = (idx < NBKT) ? hist[idx] : 0;
            int orig = v;
#pragma unroll
            for (int off = 1; off < 64; off <<= 1) {
                int t = __shfl_up(v, off);
                if (tid >= off) v += t;
            }
            if (idx < NBKT) {
                start[idx] = base + v - orig;
                wcur[idx]  = base + v - orig;
            }
            base += __shfl(v, 63);
        }
    }
    __syncthreads();

    // Publish offset row contiguously (coalesced streaming write).
    for (int i = tid; i < NBKT; i += PT) bs_t[pb * BSROW + i] = start[i];
    if (tid == 0) bs_t[pb * BSROW + NBKT] = BLK_RECS;

    // Scatter records into LDS in bucket-sorted order.
#pragma unroll
    for (int k = 0; k < EPT; ++k) {
        int d  = dsts[k];
        int b  = d / NB;
        int dl = d - b * NB;
        int slot = atomicAdd(&wcur[b], 1);
        srec[slot] = make_uint2((unsigned)srcs[k] | ((unsigned)dl << 17),
                                __float_as_uint(wts[k]));
    }
    __syncthreads();

    // Stream the sorted block to global — fully coalesced.
    uint2* dst = recs + (size_t)pb * BLK_RECS;
    for (int j = tid; j < BLK_RECS; j += PT) dst[j] = srec[j];
}

// ---------------------------------------------------------------------------
// find_run: rare-path binary search (f >= RUNOF_CAP only).
// ---------------------------------------------------------------------------
__device__ __forceinline__ int find_run(const int* pfx, int f) {
    int lo = 0, hi = PB;
    while (hi - lo > 1) {
        int m = (lo + hi) >> 1;
        if (pfx[m] <= f) lo = m; else hi = m;
    }
    return lo;
}

// ---------------------------------------------------------------------------
// FUSED layer-1 aggregation + per-node MLP for bucket b = blockIdx.x.
// Also compacts the bucket's records to crecs[b*CAP2..] and publishes
// cnts[b], so agg2 streams contiguously with no run-walk.
// ---------------------------------------------------------------------------
__global__ __launch_bounds__(CT) void fused_kernel(
    const uint2* __restrict__ recs, const int* __restrict__ bs_t,
    const float* __restrict__ x, const float* __restrict__ packed,
    const float* __restrict__ b2, float* __restrict__ s_rel,
    float* __restrict__ out, uint2* __restrict__ crecs,
    int* __restrict__ cnts) {
    __shared__ float accf[NB * 4];         // 6.4 KB
    __shared__ int   rbase[PB];
    __shared__ int   lenA[PB];
    __shared__ int   pfx[PB + 1];
    __shared__ short run_of[RUNOF_CAP];    // 6 KB

    const int tid = threadIdx.x;
    const int b   = blockIdx.x;

    for (int i = tid; i < NB * 4; i += CT) accf[i] = 0.f;

    // Build run index (strided reads of the transposed bs).
    if (tid < PB) {
        const int* row = bs_t + tid * BSROW;
        int s = row[b];
        int e = row[b + 1];
        rbase[tid] = tid * BLK_RECS + s;
        lenA[tid]  = e - s;
    }
    __syncthreads();
    if (tid < 64) {
        int base = 0;
        for (int c = 0; c < PB; c += 64) {
            int idx = c + tid;
            int v = (idx < PB) ? lenA[idx] : 0;
            int orig = v;
#pragma unroll
            for (int off = 1; off < 64; off <<= 1) {
                int t = __shfl_up(v, off);
                if (tid >= off) v += t;
            }
            if (idx < PB) pfx[idx] = base + v - orig;
            base += __shfl(v, 63);
        }
        if (tid == 0) pfx[PB] = base;
    }
    __syncthreads();
    const int cnt = pfx[PB];
    if (tid == 0) cnts[b] = cnt;
    if (tid < PB) {
        int s = pfx[tid];
        int e = pfx[tid + 1];
        if (e > RUNOF_CAP) e = RUNOF_CAP;
        for (int j = s; j < e; ++j) run_of[j] = (short)tid;
    }
    __syncthreads();

    // Gather records, accumulate layer-1 messages, compact to crecs.
    for (int f = tid; f < cnt; f += CT) {
        int rn = (f < RUNOF_CAP) ? (int)run_of[f] : find_run(pfx, f);
        uint2 rec = recs[(size_t)rbase[rn] + (f - pfx[rn])];
        if (f < CAP2) crecs[(size_t)b * CAP2 + f] = rec;
        int src = rec.x & 0x1FFFF;
        int dl  = rec.x >> 17;
        float w = __uint_as_float(rec.y);
        float4 xv = reinterpret_cast<const float4*>(x)[src];
        atomicAdd(&accf[dl * 4 + 0], xv.x * w);
        atomicAdd(&accf[dl * 4 + 1], xv.y * w);
        atomicAdd(&accf[dl * 4 + 2], xv.z * w);
        atomicAdd(&accf[dl * 4 + 3], xv.w * w);
    }
    __syncthreads();

    if (tid >= NB) return;
    const int n = b * NB + tid;

    float4 xv = reinterpret_cast<const float4*>(x)[n];
    float4 av = make_float4(accf[tid * 4 + 0], accf[tid * 4 + 1],
                            accf[tid * 4 + 2], accf[tid * 4 + 3]);

    const float4* pw = reinterpret_cast<const float4*>(packed);
    float srel = 0.f, sroot = 0.f;
#pragma unroll 4
    for (int j = 0; j < HIDDEN; ++j) {
        float4 wr = pw[j * 3 + 0];   // W1_rel[0..3][j]
        float4 wo = pw[j * 3 + 1];   // W1_root[0..3][j]
        float4 wb = pw[j * 3 + 2];   // b1, W2_rel, W2_root, pad
        float pre = wb.x
                  + av.x * wr.x + av.y * wr.y + av.z * wr.z + av.w * wr.w
                  + xv.x * wo.x + xv.y * wo.y + xv.z * wo.z + xv.w * wo.w;
        float h = fmaxf(pre, 0.f);
        srel  += h * wb.y;
        sroot += h * wb.z;
    }
    s_rel[n] = srel;
    out[n]   = sroot + b2[0];
}

// ---------------------------------------------------------------------------
// Layer-2 scalar aggregation for bucket b: contiguous crecs stream (fast
// path) or run-walk fallback (cnt > CAP2, statistically never).
// ---------------------------------------------------------------------------
__global__ __launch_bounds__(CT) void agg2_kernel(
    const uint2* __restrict__ recs, const int* __restrict__ bs_t,
    const uint2* __restrict__ crecs, const int* __restrict__ cnts,
    const float* __restrict__ s_rel, float* __restrict__ out) {
    __shared__ float acc[NB];

    const int tid = threadIdx.x;
    const int b   = blockIdx.x;

    for (int i = tid; i < NB; i += CT) acc[i] = 0.f;
    const int cnt = cnts[b];
    __syncthreads();

    if (cnt <= CAP2) {
        const uint2* r = crecs + (size_t)b * CAP2;
        for (int f = tid; f < cnt; f += CT) {
            uint2 rec = r[f];
            atomicAdd(&acc[rec.x >> 17],
                      s_rel[rec.x & 0x1FFFF] * __uint_as_float(rec.y));
        }
    } else {
        // Rare fallback: rebuild runs and walk them.
        __shared__ int rbase[PB];
        __shared__ int lenA[PB];
        __shared__ int pfx[PB + 1];
        if (tid < PB) {
            const int* row = bs_t + tid * BSROW;
            int s = row[b];
            int e = row[b + 1];
            rbase[tid] = tid * BLK_RECS + s;
            lenA[tid]  = e - s;
        }
        __syncthreads();
        if (tid < 64) {
            int base = 0;
            for (int c = 0; c < PB; c += 64) {
                int idx = c + tid;
                int v = (idx < PB) ? lenA[idx] : 0;
                int orig = v;
#pragma unroll
                for (int off = 1; off < 64; off <<= 1) {
                    int t = __shfl_up(v, off);
                    if (tid >= off) v += t;
                }
                if (idx < PB) pfx[idx] = base + v - orig;
                base += __shfl(v, 63);
            }
            if (tid == 0) pfx[PB] = base;
        }
        __syncthreads();
        for (int f = tid; f < cnt; f += CT) {
            int rn = find_run(pfx, f);
            uint2 rec = recs[(size_t)rbase[rn] + (f - pfx[rn])];
            atomicAdd(&acc[rec.x >> 17],
                      s_rel[rec.x & 0x1FFFF] * __uint_as_float(rec.y));
        }
    }
    __syncthreads();

    if (tid < NB)
        out[b * NB + tid] += acc[tid];
}

// ---------------------------------------------------------------------------
// Legacy fallback (ws too small): direct global-atomic path.
// ---------------------------------------------------------------------------
__global__ void prep_legacy(const float* __restrict__ W1_rel,
                            const float* __restrict__ b1,
                            const float* __restrict__ W1_root,
                            const float* __restrict__ W2_rel,
                            const float* __restrict__ W2_root,
                            float* __restrict__ packed) {
    int t = threadIdx.x;
    if (t < HIDDEN) {
        float* p = packed + t * 12;
#pragma unroll
        for (int k = 0; k < 4; ++k) p[k]     = W1_rel[k * HIDDEN + t];
#pragma unroll
        for (int k = 0; k < 4; ++k) p[4 + k] = W1_root[k * HIDDEN + t];
        p[8]  = b1[t];
        p[9]  = W2_rel[t];
        p[10] = W2_root[t];
        p[11] = 0.f;
    }
}

__global__ void scatter1_legacy(const int* __restrict__ ei, const float* __restrict__ ea,
                                const float* __restrict__ x, float* __restrict__ agg) {
    int e = blockIdx.x * blockDim.x + threadIdx.x;
    if (e >= N_EDGES) return;
    int src = ei[e], dst = ei[N_EDGES + e];
    float w = ea[e];
    float4 xv = reinterpret_cast<const float4*>(x)[src];
    atomicAdd(&agg[dst * 4 + 0], xv.x * w);
    atomicAdd(&agg[dst * 4 + 1], xv.y * w);
    atomicAdd(&agg[dst * 4 + 2], xv.z * w);
    atomicAdd(&agg[dst * 4 + 3], xv.w * w);
}

__global__ __launch_bounds__(256) void node_legacy(const float* __restrict__ x,
                            const float* __restrict__ agg,
                            const float* __restrict__ packed,
                            const float* __restrict__ b2,
                            float* __restrict__ s_rel,
                            float* __restrict__ out) {
    int n = blockIdx.x * blockDim.x + threadIdx.x;
    if (n >= N_NODES) return;
    float4 xv = reinterpret_cast<const float4*>(x)[n];
    float4 av = reinterpret_cast<const float4*>(agg)[n];
    const float4* pw = reinterpret_cast<const float4*>(packed);
    float srel = 0.f, sroot = 0.f;
#pragma unroll 4
    for (int j = 0; j < HIDDEN; ++j) {
        float4 wr = pw[j * 3 + 0];
        float4 wo = pw[j * 3 + 1];
        float4 wb = pw[j * 3 + 2];
        float pre = wb.x
                  + av.x * wr.x + av.y * wr.y + av.z * wr.z + av.w * wr.w
                  + xv.x * wo.x + xv.y * wo.y + xv.z * wo.z + xv.w * wo.w;
        float h = fmaxf(pre, 0.f);
        srel  += h * wb.y;
        sroot += h * wb.z;
    }
    s_rel[n] = srel;
    out[n]   = sroot + b2[0];
}

__global__ void scatter2_legacy(const int* __restrict__ ei, const float* __restrict__ ea,
                                const float* __restrict__ s_rel, float* __restrict__ out) {
    int e = blockIdx.x * blockDim.x + threadIdx.x;
    if (e >= N_EDGES) return;
    atomicAdd(&out[ei[N_EDGES + e]], s_rel[ei[e]] * ea[e]);
}

extern "C" void kernel_launch(void* const* d_in, const int* in_sizes, int n_in,
                              void* d_out, int out_size, void* d_ws, size_t ws_size,
                              hipStream_t stream) {
    const float* x       = (const float*)d_in[0];
    const int*   ei      = (const int*)  d_in[1];
    const float* ea      = (const float*)d_in[2];
    const float* W1_rel  = (const float*)d_in[3];
    const float* b1      = (const float*)d_in[4];
    const float* W1_root = (const float*)d_in[5];
    const float* W2_rel  = (const float*)d_in[6];
    const float* b2      = (const float*)d_in[7];
    const float* W2_root = (const float*)d_in[8];
    float* out = (float*)d_out;
    char*  ws  = (char*)d_ws;

    // ws layout: packed [1536 f] | s_rel [N f] | cnts [NBKT i] |
    //            bs_t [PB*BSROW i] | recs [E u2] | crecs [NBKT*CAP2 u2]
    float* packed = (float*)ws;
    float* s_rel  = packed + 1536;
    int*   cnts   = (int*)(s_rel + N_NODES);
    int*   bs_t   = cnts + NBKT;
    uint2* recs   = (uint2*)(bs_t + PB * BSROW);
    uint2* crecs  = recs + (size_t)N_EDGES;
    const size_t need = 1536 * 4 + (size_t)N_NODES * 4 + NBKT * 4 +
                        (size_t)PB * BSROW * 4 + (size_t)N_EDGES * 8 +
                        (size_t)NBKT * CAP2 * 8;

    if (ws_size >= need) {
        partition_kernel<<<PB, PT, 0, stream>>>(ei, ea, W1_rel, b1, W1_root,
                                                W2_rel, W2_root, recs, bs_t, packed);
        fused_kernel<<<NBKT, CT, 0, stream>>>(recs, bs_t, x, packed, b2,
                                              s_rel, out, crecs, cnts);
        agg2_kernel<<<NBKT, CT, 0, stream>>>(recs, bs_t, crecs, cnts, s_rel, out);
    } else {
        // Legacy global-atomic path; agg array lives where recs would.
        float* agg = (float*)recs;
        dim3 grdE((N_EDGES + 255) / 256);
        dim3 grdN((N_NODES + 255) / 256);
        prep_legacy<<<1, 256, 0, stream>>>(W1_rel, b1, W1_root, W2_rel, W2_root, packed);
        hipMemsetAsync(agg, 0, (size_t)N_NODES * 4 * sizeof(float), stream);
        scatter1_legacy<<<grdE, 256, 0, stream>>>(ei, ea, x, agg);
        node_legacy<<<grdN, 256, 0, stream>>>(x, agg, packed, b2, s_rel, out);
        scatter2_legacy<<<grdE, 256, 0, stream>>>(ei, ea, s_rel, out);
    }
}

// Round 12
// 46.042 us; speedup vs baseline: 1.0396x; 1.0396x over previous
//
#include <hip/hip_runtime.h>

#define N_NODES 100000
#define N_EDGES 640000
#define HIDDEN  128

#define NB    200              // nodes per bucket
#define NBKT  500              // buckets; NB*NBKT == N_NODES
#define PB    250              // partition blocks
#define PT    512              // partition threads (8 waves/block)
#define EPT   5                // edges/thread: PB*PT*EPT == N_EDGES
#define BLK_RECS (PT * EPT)    // 2560 records per partition block
#define CT    512              // consumer threads
#define RUNOF_CAP 2560         // run_of table entries (>> any realistic cnt)
#define CAP2  2048             // compacted per-bucket record capacity (21 sigma)
#define BSROW (NBKT + 1)       // bs_t row stride (incl. sentinel)

// ---------------------------------------------------------------------------
// Partition (+weight prep in block 0).
// Each block LDS-sorts its 2560 edge records by dst bucket, then:
//   - streams them to its OWN region recs[pb*2560..] (fully coalesced)
//   - writes its 501-entry offset row bs_t[pb][.] contiguously (coalesced).
// Record: x = src | (dst_local << 17), y = w bits.
// ---------------------------------------------------------------------------
__global__ __launch_bounds__(PT) void partition_kernel(
    const int* __restrict__ ei, const float* __restrict__ ea,
    const float* __restrict__ W1_rel, const float* __restrict__ b1,
    const float* __restrict__ W1_root, const float* __restrict__ W2_rel,
    const float* __restrict__ W2_root,
    uint2* __restrict__ recs, int* __restrict__ bs_t,
    float* __restrict__ packed) {
    const int tid = threadIdx.x;
    const int pb  = blockIdx.x;

    if (pb == 0 && tid < HIDDEN) {
        float* p = packed + tid * 12;
#pragma unroll
        for (int k = 0; k < 4; ++k) p[k]     = W1_rel[k * HIDDEN + tid];
#pragma unroll
        for (int k = 0; k < 4; ++k) p[4 + k] = W1_root[k * HIDDEN + tid];
        p[8]  = b1[tid];
        p[9]  = W2_rel[tid];
        p[10] = W2_root[tid];
        p[11] = 0.f;
    }

    __shared__ int   hist[NBKT];
    __shared__ int   start[NBKT];
    __shared__ int   wcur[NBKT];
    __shared__ uint2 srec[BLK_RECS];   // 20 KB

    for (int i = tid; i < NBKT; i += PT) hist[i] = 0;
    __syncthreads();

    int   dsts[EPT];
    int   srcs[EPT];
    float wts[EPT];
    const int e0 = pb * BLK_RECS + tid;
#pragma unroll
    for (int k = 0; k < EPT; ++k) {
        int e = e0 + k * PT;
        srcs[k] = ei[e];
        dsts[k] = ei[N_EDGES + e];
        wts[k]  = ea[e];
        atomicAdd(&hist[dsts[k] / NB], 1);
    }
    __syncthreads();

    // Single-wave exclusive scan of hist -> start/wcur.
    if (tid < 64) {
        int base = 0;
        for (int c = 0; c < NBKT; c += 64) {
            int idx = c + tid;
            int v = (idx < NBKT) ? hist[idx] : 0;
            int orig = v;
#pragma unroll
            for (int off = 1; off < 64; off <<= 1) {
                int t = __shfl_up(v, off);
                if (tid >= off) v += t;
            }
            if (idx < NBKT) {
                start[idx] = base + v - orig;
                wcur[idx]  = base + v - orig;
            }
            base += __shfl(v, 63);
        }
    }
    __syncthreads();

    // Publish offset row contiguously (coalesced streaming write).
    for (int i = tid; i < NBKT; i += PT) bs_t[pb * BSROW + i] = start[i];
    if (tid == 0) bs_t[pb * BSROW + NBKT] = BLK_RECS;

    // Scatter records into LDS in bucket-sorted order.
#pragma unroll
    for (int k = 0; k < EPT; ++k) {
        int d  = dsts[k];
        int b  = d / NB;
        int dl = d - b * NB;
        int slot = atomicAdd(&wcur[b], 1);
        srec[slot] = make_uint2((unsigned)srcs[k] | ((unsigned)dl << 17),
                                __float_as_uint(wts[k]));
    }
    __syncthreads();

    // Stream the sorted block to global — fully coalesced.
    uint2* dst = recs + (size_t)pb * BLK_RECS;
    for (int j = tid; j < BLK_RECS; j += PT) dst[j] = srec[j];
}

// ---------------------------------------------------------------------------
// find_run: rare-path binary search (f >= RUNOF_CAP only).
// ---------------------------------------------------------------------------
__device__ __forceinline__ int find_run(const int* pfx, int f) {
    int lo = 0, hi = PB;
    while (hi - lo > 1) {
        int m = (lo + hi) >> 1;
        if (pfx[m] <= f) lo = m; else hi = m;
    }
    return lo;
}

// ---------------------------------------------------------------------------
// FUSED layer-1 aggregation + per-node MLP for bucket b = blockIdx.x.
// Also compacts the bucket's records to crecs[b*CAP2..] and publishes
// cnts[b], so agg2 streams contiguously with no run-walk.
// ---------------------------------------------------------------------------
__global__ __launch_bounds__(CT) void fused_kernel(
    const uint2* __restrict__ recs, const int* __restrict__ bs_t,
    const float* __restrict__ x, const float* __restrict__ packed,
    const float* __restrict__ b2, float* __restrict__ s_rel,
    float* __restrict__ out, uint2* __restrict__ crecs,
    int* __restrict__ cnts) {
    __shared__ float accf[NB * 4];
    __shared__ int   rbase[PB];
    __shared__ int   lenA[PB];
    __shared__ int   pfx[PB + 1];
    __shared__ short run_of[RUNOF_CAP];

    const int tid = threadIdx.x;
    const int b   = blockIdx.x;

    for (int i = tid; i < NB * 4; i += CT) accf[i] = 0.f;

    // Build run index (strided reads of the transposed bs).
    if (tid < PB) {
        const int* row = bs_t + tid * BSROW;
        int s = row[b];
        int e = row[b + 1];
        rbase[tid] = tid * BLK_RECS + s;
        lenA[tid]  = e - s;
    }
    __syncthreads();
    if (tid < 64) {
        int base = 0;
        for (int c = 0; c < PB; c += 64) {
            int idx = c + tid;
            int v = (idx < PB) ? lenA[idx] : 0;
            int orig = v;
#pragma unroll
            for (int off = 1; off < 64; off <<= 1) {
                int t = __shfl_up(v, off);
                if (tid >= off) v += t;
            }
            if (idx < PB) pfx[idx] = base + v - orig;
            base += __shfl(v, 63);
        }
        if (tid == 0) pfx[PB] = base;
    }
    __syncthreads();
    const int cnt = pfx[PB];
    if (tid == 0) cnts[b] = cnt;
    if (tid < PB) {
        int s = pfx[tid];
        int e = pfx[tid + 1];
        if (e > RUNOF_CAP) e = RUNOF_CAP;
        for (int j = s; j < e; ++j) run_of[j] = (short)tid;
    }
    __syncthreads();

    // Gather records, accumulate layer-1 messages, compact to crecs.
    for (int f = tid; f < cnt; f += CT) {
        int rn = (f < RUNOF_CAP) ? (int)run_of[f] : find_run(pfx, f);
        uint2 rec = recs[(size_t)rbase[rn] + (f - pfx[rn])];
        if (f < CAP2) crecs[(size_t)b * CAP2 + f] = rec;
        int src = rec.x & 0x1FFFF;
        int dl  = rec.x >> 17;
        float w = __uint_as_float(rec.y);
        float4 xv = reinterpret_cast<const float4*>(x)[src];
        atomicAdd(&accf[dl * 4 + 0], xv.x * w);
        atomicAdd(&accf[dl * 4 + 1], xv.y * w);
        atomicAdd(&accf[dl * 4 + 2], xv.z * w);
        atomicAdd(&accf[dl * 4 + 3], xv.w * w);
    }
    __syncthreads();

    if (tid >= NB) return;
    const int n = b * NB + tid;

    float4 xv = reinterpret_cast<const float4*>(x)[n];
    float4 av = make_float4(accf[tid * 4 + 0], accf[tid * 4 + 1],
                            accf[tid * 4 + 2], accf[tid * 4 + 3]);

    const float4* pw = reinterpret_cast<const float4*>(packed);
    float srel = 0.f, sroot = 0.f;
#pragma unroll 4
    for (int j = 0; j < HIDDEN; ++j) {
        float4 wr = pw[j * 3 + 0];   // W1_rel[0..3][j]
        float4 wo = pw[j * 3 + 1];   // W1_root[0..3][j]
        float4 wb = pw[j * 3 + 2];   // b1, W2_rel, W2_root, pad
        float pre = wb.x
                  + av.x * wr.x + av.y * wr.y + av.z * wr.z + av.w * wr.w
                  + xv.x * wo.x + xv.y * wo.y + xv.z * wo.z + xv.w * wo.w;
        float h = fmaxf(pre, 0.f);
        srel  += h * wb.y;
        sroot += h * wb.z;
    }
    s_rel[n] = srel;
    out[n]   = sroot + b2[0];
}

// ---------------------------------------------------------------------------
// Layer-2 scalar aggregation for bucket b: contiguous crecs stream (fast
// path) or run-walk fallback (cnt > CAP2, statistically never).
// ---------------------------------------------------------------------------
__global__ __launch_bounds__(CT) void agg2_kernel(
    const uint2* __restrict__ recs, const int* __restrict__ bs_t,
    const uint2* __restrict__ crecs, const int* __restrict__ cnts,
    const float* __restrict__ s_rel, float* __restrict__ out) {
    __shared__ float acc[NB];

    const int tid = threadIdx.x;
    const int b   = blockIdx.x;

    for (int i = tid; i < NB; i += CT) acc[i] = 0.f;
    const int cnt = cnts[b];
    __syncthreads();

    if (cnt <= CAP2) {
        const uint2* r = crecs + (size_t)b * CAP2;
        for (int f = tid; f < cnt; f += CT) {
            uint2 rec = r[f];
            atomicAdd(&acc[rec.x >> 17],
                      s_rel[rec.x & 0x1FFFF] * __uint_as_float(rec.y));
        }
    } else {
        // Rare fallback: rebuild runs and walk them.
        __shared__ int rbase[PB];
        __shared__ int lenA[PB];
        __shared__ int pfx[PB + 1];
        if (tid < PB) {
            const int* row = bs_t + tid * BSROW;
            int s = row[b];
            int e = row[b + 1];
            rbase[tid] = tid * BLK_RECS + s;
            lenA[tid]  = e - s;
        }
        __syncthreads();
        if (tid < 64) {
            int base = 0;
            for (int c = 0; c < PB; c += 64) {
                int idx = c + tid;
                int v = (idx < PB) ? lenA[idx] : 0;
                int orig = v;
#pragma unroll
                for (int off = 1; off < 64; off <<= 1) {
                    int t = __shfl_up(v, off);
                    if (tid >= off) v += t;
                }
                if (idx < PB) pfx[idx] = base + v - orig;
                base += __shfl(v, 63);
            }
            if (tid == 0) pfx[PB] = base;
        }
        __syncthreads();
        for (int f = tid; f < cnt; f += CT) {
            int rn = find_run(pfx, f);
            uint2 rec = recs[(size_t)rbase[rn] + (f - pfx[rn])];
            atomicAdd(&acc[rec.x >> 17],
                      s_rel[rec.x & 0x1FFFF] * __uint_as_float(rec.y));
        }
    }
    __syncthreads();

    if (tid < NB)
        out[b * NB + tid] += acc[tid];
}

// ---------------------------------------------------------------------------
// Legacy fallback (ws too small): direct global-atomic path.
// ---------------------------------------------------------------------------
__global__ void prep_legacy(const float* __restrict__ W1_rel,
                            const float* __restrict__ b1,
                            const float* __restrict__ W1_root,
                            const float* __restrict__ W2_rel,
                            const float* __restrict__ W2_root,
                            float* __restrict__ packed) {
    int t = threadIdx.x;
    if (t < HIDDEN) {
        float* p = packed + t * 12;
#pragma unroll
        for (int k = 0; k < 4; ++k) p[k]     = W1_rel[k * HIDDEN + t];
#pragma unroll
        for (int k = 0; k < 4; ++k) p[4 + k] = W1_root[k * HIDDEN + t];
        p[8]  = b1[t];
        p[9]  = W2_rel[t];
        p[10] = W2_root[t];
        p[11] = 0.f;
    }
}

__global__ void scatter1_legacy(const int* __restrict__ ei, const float* __restrict__ ea,
                                const float* __restrict__ x, float* __restrict__ agg) {
    int e = blockIdx.x * blockDim.x + threadIdx.x;
    if (e >= N_EDGES) return;
    int src = ei[e], dst = ei[N_EDGES + e];
    float w = ea[e];
    float4 xv = reinterpret_cast<const float4*>(x)[src];
    atomicAdd(&agg[dst * 4 + 0], xv.x * w);
    atomicAdd(&agg[dst * 4 + 1], xv.y * w);
    atomicAdd(&agg[dst * 4 + 2], xv.z * w);
    atomicAdd(&agg[dst * 4 + 3], xv.w * w);
}

__global__ __launch_bounds__(256) void node_legacy(const float* __restrict__ x,
                            const float* __restrict__ agg,
                            const float* __restrict__ packed,
                            const float* __restrict__ b2,
                            float* __restrict__ s_rel,
                            float* __restrict__ out) {
    int n = blockIdx.x * blockDim.x + threadIdx.x;
    if (n >= N_NODES) return;
    float4 xv = reinterpret_cast<const float4*>(x)[n];
    float4 av = reinterpret_cast<const float4*>(agg)[n];
    const float4* pw = reinterpret_cast<const float4*>(packed);
    float srel = 0.f, sroot = 0.f;
#pragma unroll 4
    for (int j = 0; j < HIDDEN; ++j) {
        float4 wr = pw[j * 3 + 0];
        float4 wo = pw[j * 3 + 1];
        float4 wb = pw[j * 3 + 2];
        float pre = wb.x
                  + av.x * wr.x + av.y * wr.y + av.z * wr.z + av.w * wr.w
                  + xv.x * wo.x + xv.y * wo.y + xv.z * wo.z + xv.w * wo.w;
        float h = fmaxf(pre, 0.f);
        srel  += h * wb.y;
        sroot += h * wb.z;
    }
    s_rel[n] = srel;
    out[n]   = sroot + b2[0];
}

__global__ void scatter2_legacy(const int* __restrict__ ei, const float* __restrict__ ea,
                                const float* __restrict__ s_rel, float* __restrict__ out) {
    int e = blockIdx.x * blockDim.x + threadIdx.x;
    if (e >= N_EDGES) return;
    atomicAdd(&out[ei[N_EDGES + e]], s_rel[ei[e]] * ea[e]);
}

extern "C" void kernel_launch(void* const* d_in, const int* in_sizes, int n_in,
                              void* d_out, int out_size, void* d_ws, size_t ws_size,
                              hipStream_t stream) {
    const float* x       = (const float*)d_in[0];
    const int*   ei      = (const int*)  d_in[1];
    const float* ea      = (const float*)d_in[2];
    const float* W1_rel  = (const float*)d_in[3];
    const float* b1      = (const float*)d_in[4];
    const float* W1_root = (const float*)d_in[5];
    const float* W2_rel  = (const float*)d_in[6];
    const float* b2      = (const float*)d_in[7];
    const float* W2_root = (const float*)d_in[8];
    float* out = (float*)d_out;
    char*  ws  = (char*)d_ws;

    // ws layout: packed [1536 f] | s_rel [N f] | cnts [NBKT i] |
    //            bs_t [PB*BSROW i] | recs [E u2] | crecs [NBKT*CAP2 u2]
    float* packed = (float*)ws;
    float* s_rel  = packed + 1536;
    int*   cnts   = (int*)(s_rel + N_NODES);
    int*   bs_t   = cnts + NBKT;
    uint2* recs   = (uint2*)(bs_t + PB * BSROW);
    uint2* crecs  = recs + (size_t)N_EDGES;
    const size_t need = 1536 * 4 + (size_t)N_NODES * 4 + NBKT * 4 +
                        (size_t)PB * BSROW * 4 + (size_t)N_EDGES * 8 +
                        (size_t)NBKT * CAP2 * 8;

    if (ws_size >= need) {
        partition_kernel<<<PB, PT, 0, stream>>>(ei, ea, W1_rel, b1, W1_root,
                                                W2_rel, W2_root, recs, bs_t, packed);
        fused_kernel<<<NBKT, CT, 0, stream>>>(recs, bs_t, x, packed, b2,
                                              s_rel, out, crecs, cnts);
        agg2_kernel<<<NBKT, CT, 0, stream>>>(recs, bs_t, crecs, cnts, s_rel, out);
    } else {
        // Legacy global-atomic path; agg array lives where recs would.
        float* agg = (float*)recs;
        dim3 grdE((N_EDGES + 255) / 256);
        dim3 grdN((N_NODES + 255) / 256);
        prep_legacy<<<1, 256, 0, stream>>>(W1_rel, b1, W1_root, W2_rel, W2_root, packed);
        hipMemsetAsync(agg, 0, (size_t)N_NODES * 4 * sizeof(float), stream);
        scatter1_legacy<<<grdE, 256, 0, stream>>>(ei, ea, x, agg);
        node_legacy<<<grdN, 256, 0, stream>>>(x, agg, packed, b2, s_rel, out);
        scatter2_legacy<<<grdE, 256, 0, stream>>>(ei, ea, s_rel, out);
    }
}